// Round 15
// baseline (376.755 us; speedup 1.0000x reference)
//
#include <hip/hip_runtime.h>
#include <hip/hip_fp16.h>

#define NN 100000
#define NE 1600000
#define NG 64
#define BSZ 98            // nodes per bucket
#define NBUK 1021         // ceil(NN/BSZ), <= 1024 so scanB fits one block
#define SENTROW 127       // sentinel local row (> BSZ)
#define NBLK1 391         // ceil(NE/4096)
#define EPB 4096          // edges per pass-1 block

typedef __attribute__((ext_vector_type(8))) _Float16 f16x8;
typedef __attribute__((ext_vector_type(2))) _Float16 f16x2;
typedef __attribute__((ext_vector_type(4))) float f32x4;

union AFrag { f16x8 v; uint4 u; };

__device__ __forceinline__ bool finitef(float v) {
    return (__float_as_uint(v) & 0x7F800000u) != 0x7F800000u;
}
__device__ __forceinline__ unsigned int pkh(float lo, float hi) {
    f16x2 h = { (_Float16)lo, (_Float16)hi };
    return *(unsigned int*)&h;
}
__device__ __forceinline__ short f2h_bits(float f) {
    _Float16 h = (_Float16)f;
    return *(short*)&h;
}
// packed hid = max(p - q, 0): v_pk_add_f16(neg) + v_pk_max_f16
__device__ __forceinline__ unsigned int hsubmax0(unsigned int pu, unsigned int qu) {
    f16x2 hp = *(const f16x2*)&pu;
    f16x2 hq = *(const f16x2*)&qu;
    f16x2 z = { (_Float16)0, (_Float16)0 };
    f16x2 r = __builtin_elementwise_max(hp - hq, z);
    return *(unsigned int*)&r;
}

// Order-preserving float<->uint bijection: max(float) == atomicMax(uint), identity = 0.
// dec(0) = NaN (no-edge marker), handled downstream by finitef -> 0.
__device__ __forceinline__ unsigned int enc(float f) {
    unsigned int u = __float_as_uint(f);
    return (u & 0x80000000u) ? ~u : (u | 0x80000000u);
}
__device__ __forceinline__ float dec(unsigned int k) {
    unsigned int u = (k & 0x80000000u) ? (k ^ 0x80000000u) : ~k;
    return __uint_as_float(u);
}

// ---------------- bucket partition (atomic-free 2-level) ----------------
__global__ __launch_bounds__(256) void p1count(const int* __restrict__ dst,
                                               int* __restrict__ gmat) {
    __shared__ int h[NBUK];
    int tid = threadIdx.x;
    for (int i = tid; i < NBUK; i += 256) h[i] = 0;
    __syncthreads();
    int e0 = blockIdx.x * EPB;
    #pragma unroll
    for (int i = 0; i < 16; ++i) {
        int e = e0 + tid + i * 256;
        if (e < NE) atomicAdd(&h[dst[e] / BSZ], 1);
    }
    __syncthreads();
    for (int i = tid; i < NBUK; i += 256) gmat[blockIdx.x * NBUK + i] = h[i];
}

__global__ __launch_bounds__(512) void scanA(int* __restrict__ gmat, int* __restrict__ tot) {
    __shared__ int ls[512];
    int b = blockIdx.x, tid = threadIdx.x;
    int v = (tid < NBLK1) ? gmat[tid * NBUK + b] : 0;
    ls[tid] = v;
    __syncthreads();
    for (int o = 1; o < 512; o <<= 1) {
        int t = (tid >= o) ? ls[tid - o] : 0;
        __syncthreads();
        ls[tid] += t;
        __syncthreads();
    }
    if (tid < NBLK1) gmat[tid * NBUK + b] = ls[tid] - v;   // exclusive over blocks
    if (tid == 511) tot[b] = ls[511];
}

__global__ __launch_bounds__(1024) void scanB(const int* __restrict__ tot,
        int* __restrict__ base,
        unsigned int* __restrict__ gmax, unsigned int* __restrict__ gneg) {
    __shared__ int ls[1024];
    int tid = threadIdx.x;
    int v = (tid < NBUK) ? tot[tid] : 0;
    ls[tid] = v;
    __syncthreads();
    for (int o = 1; o < 1024; o <<= 1) {
        int t = (tid >= o) ? ls[tid - o] : 0;
        __syncthreads();
        ls[tid] += t;
        __syncthreads();
    }
    if (tid < NBUK) base[tid] = ls[tid] - v;
    if (tid == 1023) base[NBUK] = ls[1023];
    for (int i = tid; i < NG * 64; i += 1024) { gmax[i] = 0u; gneg[i] = 0u; }
}

__global__ __launch_bounds__(256) void p1scatter(const int* __restrict__ src,
        const int* __restrict__ dst, const int* __restrict__ gmat,
        const int* __restrict__ base, int* __restrict__ sedge) {
    __shared__ int cur[NBUK];
    int tid = threadIdx.x;
    for (int i = tid; i < NBUK; i += 256) cur[i] = base[i] + gmat[blockIdx.x * NBUK + i];
    __syncthreads();
    int e0 = blockIdx.x * EPB;
    #pragma unroll
    for (int i = 0; i < 16; ++i) {
        int e = e0 + tid + i * 256;
        if (e < NE) {
            int d = dst[e];
            int buk = d / BSZ;
            int row = d - buk * BSZ;
            int p = atomicAdd(&cur[buk], 1);
            sedge[p] = src[e] | (row << 20);    // packed: src (20b) | local row (7b)
        }
    }
}

// ---------------- layer A node tables: P = pos@(W1h+W1t)+b1, Q = pos@W1t (fp16) ----------------
__global__ __launch_bounds__(256) void uA_kernel(const float* __restrict__ pos,
        const float* __restrict__ W1, const float* __restrict__ b1,
        unsigned short* __restrict__ PA, unsigned short* __restrict__ QA) {
    __shared__ float sWp[96], sWq[96], sb[32];
    if (threadIdx.x < 96) {
        float wt = W1[96 + threadIdx.x];
        sWq[threadIdx.x] = wt;
        sWp[threadIdx.x] = W1[threadIdx.x] + wt;
    }
    if (threadIdx.x < 32) sb[threadIdx.x] = b1[threadIdx.x];
    __syncthreads();
    int n = blockIdx.x * 256 + threadIdx.x;
    if (n >= NN) return;
    float p0 = pos[n * 3 + 0], p1 = pos[n * 3 + 1], p2 = pos[n * 3 + 2];
    float P[32], Q[32];
    #pragma unroll
    for (int c = 0; c < 32; ++c) {
        P[c] = fmaf(p2, sWp[64 + c], fmaf(p1, sWp[32 + c], fmaf(p0, sWp[c], sb[c])));
        Q[c] = fmaf(p2, sWq[64 + c], fmaf(p1, sWq[32 + c], p0 * sWq[c]));
    }
    uint4* po = (uint4*)(PA + (size_t)n * 32);
    uint4* qo = (uint4*)(QA + (size_t)n * 32);
    #pragma unroll
    for (int q = 0; q < 4; ++q) {
        po[q] = make_uint4(pkh(P[8*q],P[8*q+1]), pkh(P[8*q+2],P[8*q+3]),
                           pkh(P[8*q+4],P[8*q+5]), pkh(P[8*q+6],P[8*q+7]));
        qo[q] = make_uint4(pkh(Q[8*q],Q[8*q+1]), pkh(Q[8*q+2],Q[8*q+3]),
                           pkh(Q[8*q+4],Q[8*q+5]), pkh(Q[8*q+6],Q[8*q+7]));
    }
}

// ---------------- layer B node tables (BN+ReLU fused in; accA is encoded uints) ----------------
__global__ __launch_bounds__(256) void uB_kernel(const unsigned int* __restrict__ accA,
        const float* __restrict__ ssA, const float* __restrict__ pos,
        const float* __restrict__ W1, const float* __restrict__ b1,
        unsigned short* __restrict__ PB, unsigned short* __restrict__ QB) {
    __shared__ float sW[32 * 64];
    __shared__ float sWt[3 * 64];
    __shared__ float sb[64];
    for (int i = threadIdx.x; i < 32 * 64; i += 256) sW[i] = W1[i];
    if (threadIdx.x < 192) sWt[threadIdx.x] = W1[32 * 64 + threadIdx.x];
    if (threadIdx.x < 64) sb[threadIdx.x] = b1[threadIdx.x];
    __syncthreads();
    int n = blockIdx.x * 256 + threadIdx.x;
    if (n >= NN) return;
    float h[32];
    const uint4* a4 = (const uint4*)(accA + (size_t)n * 32);
    #pragma unroll
    for (int q = 0; q < 8; ++q) {
        uint4 v = a4[q];
        unsigned int vv[4] = {v.x, v.y, v.z, v.w};
        #pragma unroll
        for (int r = 0; r < 4; ++r) {
            int c = 4 * q + r;
            float x = dec(vv[r]);
            x = finitef(x) ? x : 0.f;
            h[c] = fmaxf(fmaf(x, ssA[c], ssA[32 + c]), 0.f);
        }
    }
    float p0 = pos[n * 3 + 0], p1 = pos[n * 3 + 1], p2 = pos[n * 3 + 2];
    float Q[64], P[64];
    #pragma unroll
    for (int c = 0; c < 64; ++c) {
        Q[c] = fmaf(p2, sWt[128 + c], fmaf(p1, sWt[64 + c], p0 * sWt[c]));
        P[c] = Q[c] + sb[c];
    }
    #pragma unroll
    for (int k = 0; k < 32; ++k) {
        float x = h[k];
        #pragma unroll
        for (int c = 0; c < 64; ++c) P[c] = fmaf(x, sW[k * 64 + c], P[c]);
    }
    uint4* po = (uint4*)(PB + (size_t)n * 64);
    uint4* qo = (uint4*)(QB + (size_t)n * 64);
    #pragma unroll
    for (int q = 0; q < 8; ++q) {
        po[q] = make_uint4(pkh(P[8*q],P[8*q+1]), pkh(P[8*q+2],P[8*q+3]),
                           pkh(P[8*q+4],P[8*q+5]), pkh(P[8*q+6],P[8*q+7]));
        qo[q] = make_uint4(pkh(Q[8*q],Q[8*q+1]), pkh(Q[8*q+2],Q[8*q+3]),
                           pkh(Q[8*q+4],Q[8*q+5]), pkh(Q[8*q+6],Q[8*q+7]));
    }
}

// ---------------- Layer A edges: 256-thread bucket-exclusive; software-pipelined gather;
//                  fp16 hid; MFMA f16; bank-spread LDS atomics; fused flush ----------------
__global__ __launch_bounds__(256, 4) void edgeA(
        const unsigned short* __restrict__ PA, const unsigned short* __restrict__ QA,
        const int* __restrict__ sedge, const int* __restrict__ bbase,
        const float* __restrict__ W2, const float* __restrict__ b2,
        unsigned int* __restrict__ accA, float* __restrict__ partials) {
    __shared__ __align__(16) short w2f[2 * 64 * 8];
    __shared__ unsigned int nm[32 * 99];      // [ch][row], stride 99 -> bank-spread
    __shared__ float psum[256], psq[256];

    const int tid = threadIdx.x;
    const int b   = blockIdx.x;
    const int nb0 = b * BSZ;
    const int lane = tid & 63, wv = tid >> 6;   // 4 waves
    const int kg = lane >> 4;

    #pragma unroll
    for (int ii = 0; ii < 4; ++ii) {
        int i = tid + ii * 256;
        int j = i & 7, ln = (i >> 3) & 63, t = (i >> 9) & 1;
        int k = ((ln >> 4) & 3) * 8 + j, col = (ln & 15) + 16 * t;
        w2f[i] = f2h_bits(W2[k * 32 + col]);
    }
    for (int i = tid; i < 32 * 99; i += 256) nm[i] = 0;
    __syncthreads();

    float b2v[2];
    #pragma unroll
    for (int t = 0; t < 2; ++t) b2v[t] = b2[(lane & 15) + 16 * t];

    const int bs = bbase[b], be = bbase[b + 1];
    int idx = bs + wv * 64 + lane;
    int myed = (idx < be) ? sedge[idx] : (SENTROW << 20);

    // prologue: distribute + gather fragments for first iteration
    AFrag af[4]; unsigned int rw4[4];
    #pragma unroll
    for (int g = 0; g < 4; ++g) {
        int eg = __shfl(myed, g * 16 + (lane & 15), 64);
        unsigned int p = 0;
        #pragma unroll
        for (int r = 0; r < 4; ++r) {
            int e2 = __shfl(myed, g * 16 + kg * 4 + r, 64);
            p |= ((unsigned int)(e2 >> 20) & 0xFFu) << (8 * r);
        }
        rw4[g] = p;
        int s = eg & 0xFFFFF;
        int rq = min(eg >> 20, BSZ - 1);
        uint4 Pq = *(const uint4*)&PA[(size_t)s * 32 + kg * 8];
        uint4 Qq = *(const uint4*)&QA[(size_t)(nb0 + rq) * 32 + kg * 8];
        af[g].u = make_uint4(hsubmax0(Pq.x, Qq.x), hsubmax0(Pq.y, Qq.y),
                             hsubmax0(Pq.z, Qq.z), hsubmax0(Pq.w, Qq.w));
    }

    for (int e0 = bs; e0 < be; e0 += 256) {
        int nxt = (idx + 256 < be) ? sedge[idx + 256] : (SENTROW << 20);
        idx += 256;

        // prefetch next iteration's fragments (loads fly under current MFMA/atomics)
        AFrag afn[4]; unsigned int rwn[4];
        #pragma unroll
        for (int g = 0; g < 4; ++g) {
            int eg = __shfl(nxt, g * 16 + (lane & 15), 64);
            unsigned int p = 0;
            #pragma unroll
            for (int r = 0; r < 4; ++r) {
                int e2 = __shfl(nxt, g * 16 + kg * 4 + r, 64);
                p |= ((unsigned int)(e2 >> 20) & 0xFFu) << (8 * r);
            }
            rwn[g] = p;
            int s = eg & 0xFFFFF;
            int rq = min(eg >> 20, BSZ - 1);
            uint4 Pq = *(const uint4*)&PA[(size_t)s * 32 + kg * 8];
            uint4 Qq = *(const uint4*)&QA[(size_t)(nb0 + rq) * 32 + kg * 8];
            afn[g].u = make_uint4(hsubmax0(Pq.x, Qq.x), hsubmax0(Pq.y, Qq.y),
                                  hsubmax0(Pq.z, Qq.z), hsubmax0(Pq.w, Qq.w));
        }

        #pragma unroll
        for (int t = 0; t < 2; ++t) {
            f16x8 bfr = *(const f16x8*)&w2f[(t * 64 + lane) * 8];
            int ch = t * 16 + (lane & 15);
            #pragma unroll
            for (int g = 0; g < 4; ++g) {
                f32x4 c = {b2v[t], b2v[t], b2v[t], b2v[t]};
                f32x4 acc = __builtin_amdgcn_mfma_f32_16x16x32_f16(af[g].v, bfr, c, 0, 0, 0);
                #pragma unroll
                for (int r = 0; r < 4; ++r) {
                    int rr = (rw4[g] >> (8 * r)) & 0xFF;
                    if (rr < BSZ) atomicMax(&nm[ch * 99 + rr], enc(acc[r]));
                }
            }
        }
        #pragma unroll
        for (int g = 0; g < 4; ++g) { af[g] = afn[g]; rw4[g] = rwn[g]; }
        myed = nxt;
    }

    __syncthreads();
    // flush: write accA (exclusive owner) + BN partial sums over this bucket's nodes
    {
        int c = tid & 31, sub = tid >> 5;            // 8 row-groups
        float s = 0.f, q = 0.f;
        for (int nl = sub; nl < BSZ; nl += 8) {
            int n = nb0 + nl;
            if (n >= NN) break;
            unsigned int k = nm[c * 99 + nl];
            accA[(size_t)n * 32 + c] = k;
            float v = dec(k);
            v = finitef(v) ? v : 0.f;
            s += v; q = fmaf(v, v, q);
        }
        psum[tid] = s; psq[tid] = q;
    }
    __syncthreads();
    if (tid < 128) { psum[tid] += psum[tid + 128]; psq[tid] += psq[tid + 128]; }
    __syncthreads();
    if (tid < 64)  { psum[tid] += psum[tid + 64];  psq[tid] += psq[tid + 64]; }
    __syncthreads();
    if (tid < 32) {
        partials[b * 64 + tid]      = psum[tid] + psum[tid + 32];
        partials[b * 64 + 32 + tid] = psq[tid]  + psq[tid + 32];
    }
}

// ---------------- Layer B edges: 256-thread block, pipelined gather, 64 channels, K=64;
//                  flush = BN partials + graph pool (accB never global) ----------------
__global__ __launch_bounds__(256, 4) void edgeB(
        const unsigned short* __restrict__ PB, const unsigned short* __restrict__ QB,
        const int* __restrict__ sedge, const int* __restrict__ bbase,
        const int* __restrict__ batch,
        const float* __restrict__ W2, const float* __restrict__ b2,
        float* __restrict__ partials,
        unsigned int* __restrict__ gmax, unsigned int* __restrict__ gneg) {
    __shared__ __align__(16) short w2f[2 * 4 * 64 * 8];
    __shared__ unsigned int nm[64 * 99];      // [ch][row], stride 99
    __shared__ float psum[256], psq[256];

    const int tid = threadIdx.x;
    const int b   = blockIdx.x;
    const int nb0 = b * BSZ;
    const int lane = tid & 63, wv = tid >> 6;   // 4 waves
    const int kg = lane >> 4;

    #pragma unroll
    for (int ii = 0; ii < 16; ++ii) {
        int i = tid + ii * 256;
        int j = i & 7, ln = (i >> 3) & 63, t = (i >> 9) & 3, ks = (i >> 11) & 1;
        int k = ks * 32 + ((ln >> 4) & 3) * 8 + j, col = (ln & 15) + 16 * t;
        w2f[i] = f2h_bits(W2[k * 64 + col]);
    }
    for (int i = tid; i < 64 * 99; i += 256) nm[i] = 0;
    __syncthreads();

    float b2v[4];
    #pragma unroll
    for (int t = 0; t < 4; ++t) b2v[t] = b2[(lane & 15) + 16 * t];

    const int bs = bbase[b], be = bbase[b + 1];
    int idx = bs + wv * 64 + lane;
    int myed = (idx < be) ? sedge[idx] : (SENTROW << 20);

    AFrag af[4][2]; unsigned int rw4[4];
    #pragma unroll
    for (int g = 0; g < 4; ++g) {
        int eg = __shfl(myed, g * 16 + (lane & 15), 64);
        unsigned int p = 0;
        #pragma unroll
        for (int r = 0; r < 4; ++r) {
            int e2 = __shfl(myed, g * 16 + kg * 4 + r, 64);
            p |= ((unsigned int)(e2 >> 20) & 0xFFu) << (8 * r);
        }
        rw4[g] = p;
        int s = eg & 0xFFFFF;
        int rq = min(eg >> 20, BSZ - 1);
        #pragma unroll
        for (int ks = 0; ks < 2; ++ks) {
            uint4 Pq = *(const uint4*)&PB[(size_t)s * 64 + ks * 32 + kg * 8];
            uint4 Qq = *(const uint4*)&QB[(size_t)(nb0 + rq) * 64 + ks * 32 + kg * 8];
            af[g][ks].u = make_uint4(hsubmax0(Pq.x, Qq.x), hsubmax0(Pq.y, Qq.y),
                                     hsubmax0(Pq.z, Qq.z), hsubmax0(Pq.w, Qq.w));
        }
    }

    for (int e0 = bs; e0 < be; e0 += 256) {
        int nxt = (idx + 256 < be) ? sedge[idx + 256] : (SENTROW << 20);
        idx += 256;

        AFrag afn[4][2]; unsigned int rwn[4];
        #pragma unroll
        for (int g = 0; g < 4; ++g) {
            int eg = __shfl(nxt, g * 16 + (lane & 15), 64);
            unsigned int p = 0;
            #pragma unroll
            for (int r = 0; r < 4; ++r) {
                int e2 = __shfl(nxt, g * 16 + kg * 4 + r, 64);
                p |= ((unsigned int)(e2 >> 20) & 0xFFu) << (8 * r);
            }
            rwn[g] = p;
            int s = eg & 0xFFFFF;
            int rq = min(eg >> 20, BSZ - 1);
            #pragma unroll
            for (int ks = 0; ks < 2; ++ks) {
                uint4 Pq = *(const uint4*)&PB[(size_t)s * 64 + ks * 32 + kg * 8];
                uint4 Qq = *(const uint4*)&QB[(size_t)(nb0 + rq) * 64 + ks * 32 + kg * 8];
                afn[g][ks].u = make_uint4(hsubmax0(Pq.x, Qq.x), hsubmax0(Pq.y, Qq.y),
                                          hsubmax0(Pq.z, Qq.z), hsubmax0(Pq.w, Qq.w));
            }
        }

        #pragma unroll
        for (int t = 0; t < 4; ++t) {
            f16x8 bf0 = *(const f16x8*)&w2f[((0 * 4 + t) * 64 + lane) * 8];
            f16x8 bf1 = *(const f16x8*)&w2f[((1 * 4 + t) * 64 + lane) * 8];
            int ch = t * 16 + (lane & 15);
            #pragma unroll
            for (int g = 0; g < 4; ++g) {
                f32x4 c = {b2v[t], b2v[t], b2v[t], b2v[t]};
                c = __builtin_amdgcn_mfma_f32_16x16x32_f16(af[g][0].v, bf0, c, 0, 0, 0);
                f32x4 acc = __builtin_amdgcn_mfma_f32_16x16x32_f16(af[g][1].v, bf1, c, 0, 0, 0);
                #pragma unroll
                for (int r = 0; r < 4; ++r) {
                    int rr = (rw4[g] >> (8 * r)) & 0xFF;
                    if (rr < BSZ) atomicMax(&nm[ch * 99 + rr], enc(acc[r]));
                }
            }
        }
        #pragma unroll
        for (int g = 0; g < 4; ++g) {
            af[g][0] = afn[g][0]; af[g][1] = afn[g][1]; rw4[g] = rwn[g];
        }
        myed = nxt;
    }

    __syncthreads();
    // flush: BN partial sums + graph raw max/-min pool (batch sorted -> run-max)
    {
        int c = tid & 63, sub = tid >> 6;            // 4 row-groups
        float s = 0.f, q = 0.f;
        float rmax = 0.f, rneg = 0.f; int curg = -1;
        for (int nl = sub; nl < BSZ; nl += 4) {
            int n = nb0 + nl;
            if (n >= NN) break;
            float v = dec(nm[c * 99 + nl]);
            v = finitef(v) ? v : 0.f;
            s += v; q = fmaf(v, v, q);
            int g = batch[n];
            if (g != curg) {
                if (curg >= 0) {
                    atomicMax(&gmax[curg * 64 + c], enc(rmax));
                    atomicMax(&gneg[curg * 64 + c], enc(rneg));
                }
                curg = g; rmax = v; rneg = -v;
            } else {
                rmax = fmaxf(rmax, v); rneg = fmaxf(rneg, -v);
            }
        }
        if (curg >= 0) {
            atomicMax(&gmax[curg * 64 + c], enc(rmax));
            atomicMax(&gneg[curg * 64 + c], enc(rneg));
        }
        psum[tid] = s; psq[tid] = q;
    }
    __syncthreads();
    if (tid < 128) { psum[tid] += psum[tid + 128]; psq[tid] += psq[tid + 128]; }
    __syncthreads();
    if (tid < 64) {
        partials[b * 128 + tid]      = psum[tid] + psum[tid + 64];
        partials[b * 128 + 64 + tid] = psq[tid]  + psq[tid + 64];
    }
}

// ---------------- parallel final BN reduction: 1024 threads, chunked + tree ----------------
template <int C>
__global__ __launch_bounds__(1024) void bn_final(const float* __restrict__ partials, int nblocks,
                         const float* __restrict__ gamma, const float* __restrict__ beta,
                         float* __restrict__ ss) {
    __shared__ float lsum[1024], lsq[1024];
    const int NCH = 1024 / C;
    int tid = threadIdx.x;
    int c = tid & (C - 1);
    int chunk = tid / C;
    float s = 0.f, q = 0.f;
    for (int b = chunk; b < nblocks; b += NCH) {
        s += partials[b * 2 * C + c];
        q += partials[b * 2 * C + C + c];
    }
    lsum[chunk * C + c] = s; lsq[chunk * C + c] = q;
    __syncthreads();
    #pragma unroll
    for (int o = 512; o >= C; o >>= 1) {
        if (tid < o && o >= C) {
            lsum[tid] += lsum[tid + o];
            lsq[tid]  += lsq[tid + o];
        }
        __syncthreads();
    }
    if (tid < C) {
        float mu  = lsum[tid] / (float)NN;
        float var = fmaxf(lsq[tid] / (float)NN - mu * mu, 0.f);
        float inv = rsqrtf(var + 1e-5f);
        float sc  = gamma[tid] * inv;
        ss[tid]     = sc;
        ss[C + tid] = fmaf(-mu, sc, beta[tid]);
    }
}

// ---------------- final: BN affine+relu on pooled extrema, then 64x64x2 GEMM ----------------
__global__ void final_gemm(const unsigned int* __restrict__ gmax,
                           const unsigned int* __restrict__ gneg,
                           const float* __restrict__ ss, const float* __restrict__ Wc,
                           const float* __restrict__ bc, float* __restrict__ out) {
    int t = threadIdx.x;
    if (t >= NG * 2) return;
    int g = t >> 1, o = t & 1;
    float s = bc[o];
    for (int k = 0; k < 64; ++k) {
        float sc = ss[k], sh = ss[64 + k];
        float xm = dec(gmax[g * 64 + k]), xn = dec(gneg[g * 64 + k]);
        float x = (sc >= 0.f) ? xm : -xn;
        float v = finitef(x) ? fmaxf(fmaf(sc, x, sh), 0.f) : 0.f;   // empty graph -> 0
        s = fmaf(v, Wc[k * 2 + o], s);
    }
    out[t] = s;
}

extern "C" void kernel_launch(void* const* d_in, const int* in_sizes, int n_in,
                              void* d_out, int out_size, void* d_ws, size_t ws_size,
                              hipStream_t stream) {
    const float* pos   = (const float*)d_in[0];
    const int*   ei    = (const int*)d_in[1];
    const int*   batch = (const int*)d_in[2];
    const float* W1a = (const float*)d_in[3];
    const float* b1a = (const float*)d_in[4];
    const float* W2a = (const float*)d_in[5];
    const float* b2a = (const float*)d_in[6];
    const float* g1  = (const float*)d_in[7];
    const float* be1 = (const float*)d_in[8];
    const float* W1b = (const float*)d_in[9];
    const float* b1b = (const float*)d_in[10];
    const float* W2b = (const float*)d_in[11];
    const float* b2b = (const float*)d_in[12];
    const float* g2  = (const float*)d_in[13];
    const float* be2 = (const float*)d_in[14];
    const float* Wc  = (const float*)d_in[15];
    const float* bc  = (const float*)d_in[16];
    const int* srcp = ei;
    const int* dstp = ei + NE;

    char* base_p = (char*)d_ws;
    size_t ofs = 0;
    auto alloc = [&](size_t bytes) { char* p = base_p + ofs; ofs = (ofs + bytes + 255) & ~(size_t)255; return p; };
    int*   gmat  = (int*)alloc((size_t)NBLK1 * NBUK * 4);
    int*   tot   = (int*)alloc(NBUK * 4);
    int*   bbase = (int*)alloc((NBUK + 1) * 4);
    int*   sedge = (int*)alloc((size_t)NE * 4);                       // packed src|row, 6.4 MB
    unsigned short* PA = (unsigned short*)alloc((size_t)NN * 32 * 2);
    unsigned short* QA = (unsigned short*)alloc((size_t)NN * 32 * 2);
    unsigned short* PB = PA;                                           // spans PA+QA (12.8 MB)
    unsigned short* QB = (unsigned short*)alloc((size_t)NN * 64 * 2);
    unsigned int* accA = (unsigned int*)alloc((size_t)NN * 32 * 4);   // written fully by edgeA flush
    float* partA = (float*)alloc((size_t)NBUK * 64 * 4);
    float* partB = (float*)alloc((size_t)NBUK * 128 * 4);
    float* ssA   = (float*)alloc(64 * 4);
    float* ssB   = (float*)alloc(128 * 4);
    unsigned int* gmax = (unsigned int*)alloc(NG * 64 * 4);
    unsigned int* gneg = (unsigned int*)alloc(NG * 64 * 4);

    // bucket partition (also inits gmax/gneg)
    p1count<<<NBLK1, 256, 0, stream>>>(dstp, gmat);
    scanA<<<NBUK, 512, 0, stream>>>(gmat, tot);
    scanB<<<1, 1024, 0, stream>>>(tot, bbase, gmax, gneg);
    p1scatter<<<NBLK1, 256, 0, stream>>>(srcp, dstp, gmat, bbase, sedge);

    // Layer A (edgeA flush writes accA + BN partials)
    uA_kernel<<<(NN + 255) / 256, 256, 0, stream>>>(pos, W1a, b1a, PA, QA);
    edgeA<<<NBUK, 256, 0, stream>>>(PA, QA, sedge, bbase, W2a, b2a, accA, partA);
    bn_final<32><<<1, 1024, 0, stream>>>(partA, NBUK, g1, be1, ssA);

    // Layer B (edgeB flush computes BN partials + graph pool; accB never materialized)
    uB_kernel<<<(NN + 255) / 256, 256, 0, stream>>>(accA, ssA, pos, W1b, b1b, PB, QB);
    edgeB<<<NBUK, 256, 0, stream>>>(PB, QB, sedge, bbase, batch, W2b, b2b, partB, gmax, gneg);
    bn_final<64><<<1, 1024, 0, stream>>>(partB, NBUK, g2, be2, ssB);
    final_gemm<<<1, 128, 0, stream>>>(gmax, gneg, ssB, Wc, bc, (float*)d_out);
}

// Round 16
// 251.321 us; speedup vs baseline: 1.4991x; 1.4991x over previous
//
#include <hip/hip_runtime.h>
#include <hip/hip_fp16.h>

#define NN 100000
#define NE 1600000
#define NG 64
#define BSZ 98            // nodes per bucket
#define NBUK 1021         // ceil(NN/BSZ), <= 1024 so scanB fits one block
#define SENTROW 127       // sentinel local row (> BSZ)
#define NBLK1 391         // ceil(NE/4096)
#define EPB 4096          // edges per pass-1 block

typedef __attribute__((ext_vector_type(8))) _Float16 f16x8;
typedef __attribute__((ext_vector_type(2))) _Float16 f16x2;
typedef __attribute__((ext_vector_type(4))) float f32x4;

union AFrag { f16x8 v; uint4 u; };

__device__ __forceinline__ bool finitef(float v) {
    return (__float_as_uint(v) & 0x7F800000u) != 0x7F800000u;
}
__device__ __forceinline__ unsigned int pkh(float lo, float hi) {
    f16x2 h = { (_Float16)lo, (_Float16)hi };
    return *(unsigned int*)&h;
}
__device__ __forceinline__ short f2h_bits(float f) {
    _Float16 h = (_Float16)f;
    return *(short*)&h;
}
// packed hid = max(p - q, 0): v_pk_add_f16(neg) + v_pk_max_f16
__device__ __forceinline__ unsigned int hsubmax0(unsigned int pu, unsigned int qu) {
    f16x2 hp = *(const f16x2*)&pu;
    f16x2 hq = *(const f16x2*)&qu;
    f16x2 z = { (_Float16)0, (_Float16)0 };
    f16x2 r = __builtin_elementwise_max(hp - hq, z);
    return *(unsigned int*)&r;
}

// Order-preserving float<->uint bijection: max(float) == atomicMax(uint), identity = 0.
// dec(0) = NaN (no-edge marker), handled downstream by finitef -> 0.
__device__ __forceinline__ unsigned int enc(float f) {
    unsigned int u = __float_as_uint(f);
    return (u & 0x80000000u) ? ~u : (u | 0x80000000u);
}
__device__ __forceinline__ float dec(unsigned int k) {
    unsigned int u = (k & 0x80000000u) ? (k ^ 0x80000000u) : ~k;
    return __uint_as_float(u);
}

// ---------------- bucket partition (atomic-free 2-level) ----------------
__global__ __launch_bounds__(256) void p1count(const int* __restrict__ dst,
                                               int* __restrict__ gmat) {
    __shared__ int h[NBUK];
    int tid = threadIdx.x;
    for (int i = tid; i < NBUK; i += 256) h[i] = 0;
    __syncthreads();
    int e0 = blockIdx.x * EPB;
    #pragma unroll
    for (int i = 0; i < 16; ++i) {
        int e = e0 + tid + i * 256;
        if (e < NE) atomicAdd(&h[dst[e] / BSZ], 1);
    }
    __syncthreads();
    for (int i = tid; i < NBUK; i += 256) gmat[blockIdx.x * NBUK + i] = h[i];
}

__global__ __launch_bounds__(512) void scanA(int* __restrict__ gmat, int* __restrict__ tot) {
    __shared__ int ls[512];
    int b = blockIdx.x, tid = threadIdx.x;
    int v = (tid < NBLK1) ? gmat[tid * NBUK + b] : 0;
    ls[tid] = v;
    __syncthreads();
    for (int o = 1; o < 512; o <<= 1) {
        int t = (tid >= o) ? ls[tid - o] : 0;
        __syncthreads();
        ls[tid] += t;
        __syncthreads();
    }
    if (tid < NBLK1) gmat[tid * NBUK + b] = ls[tid] - v;   // exclusive over blocks
    if (tid == 511) tot[b] = ls[511];
}

__global__ __launch_bounds__(1024) void scanB(const int* __restrict__ tot,
        int* __restrict__ base,
        unsigned int* __restrict__ gmax, unsigned int* __restrict__ gneg) {
    __shared__ int ls[1024];
    int tid = threadIdx.x;
    int v = (tid < NBUK) ? tot[tid] : 0;
    ls[tid] = v;
    __syncthreads();
    for (int o = 1; o < 1024; o <<= 1) {
        int t = (tid >= o) ? ls[tid - o] : 0;
        __syncthreads();
        ls[tid] += t;
        __syncthreads();
    }
    if (tid < NBUK) base[tid] = ls[tid] - v;
    if (tid == 1023) base[NBUK] = ls[1023];
    for (int i = tid; i < NG * 64; i += 1024) { gmax[i] = 0u; gneg[i] = 0u; }
}

__global__ __launch_bounds__(256) void p1scatter(const int* __restrict__ src,
        const int* __restrict__ dst, const int* __restrict__ gmat,
        const int* __restrict__ base, int* __restrict__ sedge) {
    __shared__ int cur[NBUK];
    int tid = threadIdx.x;
    for (int i = tid; i < NBUK; i += 256) cur[i] = base[i] + gmat[blockIdx.x * NBUK + i];
    __syncthreads();
    int e0 = blockIdx.x * EPB;
    #pragma unroll
    for (int i = 0; i < 16; ++i) {
        int e = e0 + tid + i * 256;
        if (e < NE) {
            int d = dst[e];
            int buk = d / BSZ;
            int row = d - buk * BSZ;
            int p = atomicAdd(&cur[buk], 1);
            sedge[p] = src[e] | (row << 20);    // packed: src (20b) | local row (7b)
        }
    }
}

// ---------------- layer A node tables: P = pos@(W1h+W1t)+b1, Q = pos@W1t (fp16) ----------------
__global__ __launch_bounds__(256) void uA_kernel(const float* __restrict__ pos,
        const float* __restrict__ W1, const float* __restrict__ b1,
        unsigned short* __restrict__ PA, unsigned short* __restrict__ QA) {
    __shared__ float sWp[96], sWq[96], sb[32];
    if (threadIdx.x < 96) {
        float wt = W1[96 + threadIdx.x];
        sWq[threadIdx.x] = wt;
        sWp[threadIdx.x] = W1[threadIdx.x] + wt;
    }
    if (threadIdx.x < 32) sb[threadIdx.x] = b1[threadIdx.x];
    __syncthreads();
    int n = blockIdx.x * 256 + threadIdx.x;
    if (n >= NN) return;
    float p0 = pos[n * 3 + 0], p1 = pos[n * 3 + 1], p2 = pos[n * 3 + 2];
    float P[32], Q[32];
    #pragma unroll
    for (int c = 0; c < 32; ++c) {
        P[c] = fmaf(p2, sWp[64 + c], fmaf(p1, sWp[32 + c], fmaf(p0, sWp[c], sb[c])));
        Q[c] = fmaf(p2, sWq[64 + c], fmaf(p1, sWq[32 + c], p0 * sWq[c]));
    }
    uint4* po = (uint4*)(PA + (size_t)n * 32);
    uint4* qo = (uint4*)(QA + (size_t)n * 32);
    #pragma unroll
    for (int q = 0; q < 4; ++q) {
        po[q] = make_uint4(pkh(P[8*q],P[8*q+1]), pkh(P[8*q+2],P[8*q+3]),
                           pkh(P[8*q+4],P[8*q+5]), pkh(P[8*q+6],P[8*q+7]));
        qo[q] = make_uint4(pkh(Q[8*q],Q[8*q+1]), pkh(Q[8*q+2],Q[8*q+3]),
                           pkh(Q[8*q+4],Q[8*q+5]), pkh(Q[8*q+6],Q[8*q+7]));
    }
}

// ---------------- layer B node tables (BN+ReLU fused in; accA is encoded uints) ----------------
__global__ __launch_bounds__(256) void uB_kernel(const unsigned int* __restrict__ accA,
        const float* __restrict__ ssA, const float* __restrict__ pos,
        const float* __restrict__ W1, const float* __restrict__ b1,
        unsigned short* __restrict__ PB, unsigned short* __restrict__ QB) {
    __shared__ float sW[32 * 64];
    __shared__ float sWt[3 * 64];
    __shared__ float sb[64];
    for (int i = threadIdx.x; i < 32 * 64; i += 256) sW[i] = W1[i];
    if (threadIdx.x < 192) sWt[threadIdx.x] = W1[32 * 64 + threadIdx.x];
    if (threadIdx.x < 64) sb[threadIdx.x] = b1[threadIdx.x];
    __syncthreads();
    int n = blockIdx.x * 256 + threadIdx.x;
    if (n >= NN) return;
    float h[32];
    const uint4* a4 = (const uint4*)(accA + (size_t)n * 32);
    #pragma unroll
    for (int q = 0; q < 8; ++q) {
        uint4 v = a4[q];
        unsigned int vv[4] = {v.x, v.y, v.z, v.w};
        #pragma unroll
        for (int r = 0; r < 4; ++r) {
            int c = 4 * q + r;
            float x = dec(vv[r]);
            x = finitef(x) ? x : 0.f;
            h[c] = fmaxf(fmaf(x, ssA[c], ssA[32 + c]), 0.f);
        }
    }
    float p0 = pos[n * 3 + 0], p1 = pos[n * 3 + 1], p2 = pos[n * 3 + 2];
    float Q[64], P[64];
    #pragma unroll
    for (int c = 0; c < 64; ++c) {
        Q[c] = fmaf(p2, sWt[128 + c], fmaf(p1, sWt[64 + c], p0 * sWt[c]));
        P[c] = Q[c] + sb[c];
    }
    #pragma unroll
    for (int k = 0; k < 32; ++k) {
        float x = h[k];
        #pragma unroll
        for (int c = 0; c < 64; ++c) P[c] = fmaf(x, sW[k * 64 + c], P[c]);
    }
    uint4* po = (uint4*)(PB + (size_t)n * 64);
    uint4* qo = (uint4*)(QB + (size_t)n * 64);
    #pragma unroll
    for (int q = 0; q < 8; ++q) {
        po[q] = make_uint4(pkh(P[8*q],P[8*q+1]), pkh(P[8*q+2],P[8*q+3]),
                           pkh(P[8*q+4],P[8*q+5]), pkh(P[8*q+6],P[8*q+7]));
        qo[q] = make_uint4(pkh(Q[8*q],Q[8*q+1]), pkh(Q[8*q+2],Q[8*q+3]),
                           pkh(Q[8*q+4],Q[8*q+5]), pkh(Q[8*q+6],Q[8*q+7]));
    }
}

// ---------------- Layer A edges: 256-thread bucket-exclusive; shfl edge distribution;
//                  fp16 hid; MFMA f16; bank-spread LDS atomics; fused flush ----------------
__global__ __launch_bounds__(256, 4) void edgeA(
        const unsigned short* __restrict__ PA, const unsigned short* __restrict__ QA,
        const int* __restrict__ sedge, const int* __restrict__ bbase,
        const float* __restrict__ W2, const float* __restrict__ b2,
        unsigned int* __restrict__ accA, float* __restrict__ partials) {
    __shared__ __align__(16) short w2f[2 * 64 * 8];
    __shared__ unsigned int nm[32 * 99];      // [ch][row], stride 99 -> bank-spread
    __shared__ float psum[256], psq[256];

    const int tid = threadIdx.x;
    const int b   = blockIdx.x;
    const int nb0 = b * BSZ;
    const int lane = tid & 63, wv = tid >> 6;   // 4 waves
    const int kg = lane >> 4;

    #pragma unroll
    for (int ii = 0; ii < 4; ++ii) {
        int i = tid + ii * 256;
        int j = i & 7, ln = (i >> 3) & 63, t = (i >> 9) & 1;
        int k = ((ln >> 4) & 3) * 8 + j, col = (ln & 15) + 16 * t;
        w2f[i] = f2h_bits(W2[k * 32 + col]);
    }
    for (int i = tid; i < 32 * 99; i += 256) nm[i] = 0;
    __syncthreads();

    float b2v[2];
    #pragma unroll
    for (int t = 0; t < 2; ++t) b2v[t] = b2[(lane & 15) + 16 * t];

    const int bs = bbase[b], be = bbase[b + 1];
    int idx = bs + wv * 64 + lane;
    int myed = (idx < be) ? sedge[idx] : (SENTROW << 20);
    for (int e0 = bs; e0 < be; e0 += 256) {
        int nxt = (idx + 256 < be) ? sedge[idx + 256] : (SENTROW << 20);
        idx += 256;

        int edg[4]; unsigned int rw4[4];
        #pragma unroll
        for (int g = 0; g < 4; ++g) {
            edg[g] = __shfl(myed, g * 16 + (lane & 15), 64);
            unsigned int p = 0;
            #pragma unroll
            for (int r = 0; r < 4; ++r) {
                int e2 = __shfl(myed, g * 16 + kg * 4 + r, 64);
                p |= ((unsigned int)(e2 >> 20) & 0xFFu) << (8 * r);
            }
            rw4[g] = p;
        }

        AFrag af[4];
        #pragma unroll
        for (int g = 0; g < 4; ++g) {
            int s = edg[g] & 0xFFFFF;
            int rq = min(edg[g] >> 20, BSZ - 1);
            uint4 Pq = *(const uint4*)&PA[(size_t)s * 32 + kg * 8];
            uint4 Qq = *(const uint4*)&QA[(size_t)(nb0 + rq) * 32 + kg * 8];
            af[g].u = make_uint4(hsubmax0(Pq.x, Qq.x), hsubmax0(Pq.y, Qq.y),
                                 hsubmax0(Pq.z, Qq.z), hsubmax0(Pq.w, Qq.w));
        }

        #pragma unroll
        for (int t = 0; t < 2; ++t) {
            f16x8 bfr = *(const f16x8*)&w2f[(t * 64 + lane) * 8];
            int ch = t * 16 + (lane & 15);
            #pragma unroll
            for (int g = 0; g < 4; ++g) {
                f32x4 c = {b2v[t], b2v[t], b2v[t], b2v[t]};
                f32x4 acc = __builtin_amdgcn_mfma_f32_16x16x32_f16(af[g].v, bfr, c, 0, 0, 0);
                #pragma unroll
                for (int r = 0; r < 4; ++r) {
                    int rr = (rw4[g] >> (8 * r)) & 0xFF;
                    if (rr < BSZ) atomicMax(&nm[ch * 99 + rr], enc(acc[r]));
                }
            }
        }
        myed = nxt;
    }

    __syncthreads();
    // flush: write accA (exclusive owner) + BN partial sums over this bucket's nodes
    {
        int c = tid & 31, sub = tid >> 5;            // 8 row-groups
        float s = 0.f, q = 0.f;
        for (int nl = sub; nl < BSZ; nl += 8) {
            int n = nb0 + nl;
            if (n >= NN) break;
            unsigned int k = nm[c * 99 + nl];
            accA[(size_t)n * 32 + c] = k;
            float v = dec(k);
            v = finitef(v) ? v : 0.f;
            s += v; q = fmaf(v, v, q);
        }
        psum[tid] = s; psq[tid] = q;
    }
    __syncthreads();
    if (tid < 128) { psum[tid] += psum[tid + 128]; psq[tid] += psq[tid + 128]; }
    __syncthreads();
    if (tid < 64)  { psum[tid] += psum[tid + 64];  psq[tid] += psq[tid + 64]; }
    __syncthreads();
    if (tid < 32) {
        partials[b * 64 + tid]      = psum[tid] + psum[tid + 32];
        partials[b * 64 + 32 + tid] = psq[tid]  + psq[tid + 32];
    }
}

// ---------------- Layer B edges: 256-thread block, 64 channels, K=64;
//                  flush = BN partials + graph pool (accB never global) ----------------
__global__ __launch_bounds__(256, 4) void edgeB(
        const unsigned short* __restrict__ PB, const unsigned short* __restrict__ QB,
        const int* __restrict__ sedge, const int* __restrict__ bbase,
        const int* __restrict__ batch,
        const float* __restrict__ W2, const float* __restrict__ b2,
        float* __restrict__ partials,
        unsigned int* __restrict__ gmax, unsigned int* __restrict__ gneg) {
    __shared__ __align__(16) short w2f[2 * 4 * 64 * 8];
    __shared__ unsigned int nm[64 * 99];      // [ch][row], stride 99
    __shared__ float psum[256], psq[256];

    const int tid = threadIdx.x;
    const int b   = blockIdx.x;
    const int nb0 = b * BSZ;
    const int lane = tid & 63, wv = tid >> 6;   // 4 waves
    const int kg = lane >> 4;

    #pragma unroll
    for (int ii = 0; ii < 16; ++ii) {
        int i = tid + ii * 256;
        int j = i & 7, ln = (i >> 3) & 63, t = (i >> 9) & 3, ks = (i >> 11) & 1;
        int k = ks * 32 + ((ln >> 4) & 3) * 8 + j, col = (ln & 15) + 16 * t;
        w2f[i] = f2h_bits(W2[k * 64 + col]);
    }
    for (int i = tid; i < 64 * 99; i += 256) nm[i] = 0;
    __syncthreads();

    float b2v[4];
    #pragma unroll
    for (int t = 0; t < 4; ++t) b2v[t] = b2[(lane & 15) + 16 * t];

    const int bs = bbase[b], be = bbase[b + 1];
    int idx = bs + wv * 64 + lane;
    int myed = (idx < be) ? sedge[idx] : (SENTROW << 20);
    for (int e0 = bs; e0 < be; e0 += 256) {
        int nxt = (idx + 256 < be) ? sedge[idx + 256] : (SENTROW << 20);
        idx += 256;

        int edg[4]; unsigned int rw4[4];
        #pragma unroll
        for (int g = 0; g < 4; ++g) {
            edg[g] = __shfl(myed, g * 16 + (lane & 15), 64);
            unsigned int p = 0;
            #pragma unroll
            for (int r = 0; r < 4; ++r) {
                int e2 = __shfl(myed, g * 16 + kg * 4 + r, 64);
                p |= ((unsigned int)(e2 >> 20) & 0xFFu) << (8 * r);
            }
            rw4[g] = p;
        }

        AFrag af[4][2];
        #pragma unroll
        for (int g = 0; g < 4; ++g) {
            int s = edg[g] & 0xFFFFF;
            int rq = min(edg[g] >> 20, BSZ - 1);
            #pragma unroll
            for (int ks = 0; ks < 2; ++ks) {
                uint4 Pq = *(const uint4*)&PB[(size_t)s * 64 + ks * 32 + kg * 8];
                uint4 Qq = *(const uint4*)&QB[(size_t)(nb0 + rq) * 64 + ks * 32 + kg * 8];
                af[g][ks].u = make_uint4(hsubmax0(Pq.x, Qq.x), hsubmax0(Pq.y, Qq.y),
                                         hsubmax0(Pq.z, Qq.z), hsubmax0(Pq.w, Qq.w));
            }
        }

        #pragma unroll
        for (int t = 0; t < 4; ++t) {
            f16x8 bf0 = *(const f16x8*)&w2f[((0 * 4 + t) * 64 + lane) * 8];
            f16x8 bf1 = *(const f16x8*)&w2f[((1 * 4 + t) * 64 + lane) * 8];
            int ch = t * 16 + (lane & 15);
            #pragma unroll
            for (int g = 0; g < 4; ++g) {
                f32x4 c = {b2v[t], b2v[t], b2v[t], b2v[t]};
                c = __builtin_amdgcn_mfma_f32_16x16x32_f16(af[g][0].v, bf0, c, 0, 0, 0);
                f32x4 acc = __builtin_amdgcn_mfma_f32_16x16x32_f16(af[g][1].v, bf1, c, 0, 0, 0);
                #pragma unroll
                for (int r = 0; r < 4; ++r) {
                    int rr = (rw4[g] >> (8 * r)) & 0xFF;
                    if (rr < BSZ) atomicMax(&nm[ch * 99 + rr], enc(acc[r]));
                }
            }
        }
        myed = nxt;
    }

    __syncthreads();
    // flush: BN partial sums + graph raw max/-min pool (batch sorted -> run-max)
    {
        int c = tid & 63, sub = tid >> 6;            // 4 row-groups
        float s = 0.f, q = 0.f;
        float rmax = 0.f, rneg = 0.f; int curg = -1;
        for (int nl = sub; nl < BSZ; nl += 4) {
            int n = nb0 + nl;
            if (n >= NN) break;
            float v = dec(nm[c * 99 + nl]);
            v = finitef(v) ? v : 0.f;
            s += v; q = fmaf(v, v, q);
            int g = batch[n];
            if (g != curg) {
                if (curg >= 0) {
                    atomicMax(&gmax[curg * 64 + c], enc(rmax));
                    atomicMax(&gneg[curg * 64 + c], enc(rneg));
                }
                curg = g; rmax = v; rneg = -v;
            } else {
                rmax = fmaxf(rmax, v); rneg = fmaxf(rneg, -v);
            }
        }
        if (curg >= 0) {
            atomicMax(&gmax[curg * 64 + c], enc(rmax));
            atomicMax(&gneg[curg * 64 + c], enc(rneg));
        }
        psum[tid] = s; psq[tid] = q;
    }
    __syncthreads();
    if (tid < 128) { psum[tid] += psum[tid + 128]; psq[tid] += psq[tid + 128]; }
    __syncthreads();
    if (tid < 64) {
        partials[b * 128 + tid]      = psum[tid] + psum[tid + 64];
        partials[b * 128 + 64 + tid] = psq[tid]  + psq[tid + 64];
    }
}

// ---------------- parallel final BN reduction: 1024 threads, chunked + tree ----------------
template <int C>
__global__ __launch_bounds__(1024) void bn_final(const float* __restrict__ partials, int nblocks,
                         const float* __restrict__ gamma, const float* __restrict__ beta,
                         float* __restrict__ ss) {
    __shared__ float lsum[1024], lsq[1024];
    const int NCH = 1024 / C;
    int tid = threadIdx.x;
    int c = tid & (C - 1);
    int chunk = tid / C;
    float s = 0.f, q = 0.f;
    for (int b = chunk; b < nblocks; b += NCH) {
        s += partials[b * 2 * C + c];
        q += partials[b * 2 * C + C + c];
    }
    lsum[chunk * C + c] = s; lsq[chunk * C + c] = q;
    __syncthreads();
    #pragma unroll
    for (int o = 512; o >= C; o >>= 1) {
        if (tid < o && o >= C) {
            lsum[tid] += lsum[tid + o];
            lsq[tid]  += lsq[tid + o];
        }
        __syncthreads();
    }
    if (tid < C) {
        float mu  = lsum[tid] / (float)NN;
        float var = fmaxf(lsq[tid] / (float)NN - mu * mu, 0.f);
        float inv = rsqrtf(var + 1e-5f);
        float sc  = gamma[tid] * inv;
        ss[tid]     = sc;
        ss[C + tid] = fmaf(-mu, sc, beta[tid]);
    }
}

// ---------------- final: BN affine+relu on pooled extrema, then 64x64x2 GEMM ----------------
__global__ void final_gemm(const unsigned int* __restrict__ gmax,
                           const unsigned int* __restrict__ gneg,
                           const float* __restrict__ ss, const float* __restrict__ Wc,
                           const float* __restrict__ bc, float* __restrict__ out) {
    int t = threadIdx.x;
    if (t >= NG * 2) return;
    int g = t >> 1, o = t & 1;
    float s = bc[o];
    for (int k = 0; k < 64; ++k) {
        float sc = ss[k], sh = ss[64 + k];
        float xm = dec(gmax[g * 64 + k]), xn = dec(gneg[g * 64 + k]);
        float x = (sc >= 0.f) ? xm : -xn;
        float v = finitef(x) ? fmaxf(fmaf(sc, x, sh), 0.f) : 0.f;   // empty graph -> 0
        s = fmaf(v, Wc[k * 2 + o], s);
    }
    out[t] = s;
}

extern "C" void kernel_launch(void* const* d_in, const int* in_sizes, int n_in,
                              void* d_out, int out_size, void* d_ws, size_t ws_size,
                              hipStream_t stream) {
    const float* pos   = (const float*)d_in[0];
    const int*   ei    = (const int*)d_in[1];
    const int*   batch = (const int*)d_in[2];
    const float* W1a = (const float*)d_in[3];
    const float* b1a = (const float*)d_in[4];
    const float* W2a = (const float*)d_in[5];
    const float* b2a = (const float*)d_in[6];
    const float* g1  = (const float*)d_in[7];
    const float* be1 = (const float*)d_in[8];
    const float* W1b = (const float*)d_in[9];
    const float* b1b = (const float*)d_in[10];
    const float* W2b = (const float*)d_in[11];
    const float* b2b = (const float*)d_in[12];
    const float* g2  = (const float*)d_in[13];
    const float* be2 = (const float*)d_in[14];
    const float* Wc  = (const float*)d_in[15];
    const float* bc  = (const float*)d_in[16];
    const int* srcp = ei;
    const int* dstp = ei + NE;

    char* base_p = (char*)d_ws;
    size_t ofs = 0;
    auto alloc = [&](size_t bytes) { char* p = base_p + ofs; ofs = (ofs + bytes + 255) & ~(size_t)255; return p; };
    int*   gmat  = (int*)alloc((size_t)NBLK1 * NBUK * 4);
    int*   tot   = (int*)alloc(NBUK * 4);
    int*   bbase = (int*)alloc((NBUK + 1) * 4);
    int*   sedge = (int*)alloc((size_t)NE * 4);                       // packed src|row, 6.4 MB
    unsigned short* PA = (unsigned short*)alloc((size_t)NN * 32 * 2);
    unsigned short* QA = (unsigned short*)alloc((size_t)NN * 32 * 2);
    unsigned short* PB = PA;                                           // spans PA+QA (12.8 MB)
    unsigned short* QB = (unsigned short*)alloc((size_t)NN * 64 * 2);
    unsigned int* accA = (unsigned int*)alloc((size_t)NN * 32 * 4);   // written fully by edgeA flush
    float* partA = (float*)alloc((size_t)NBUK * 64 * 4);
    float* partB = (float*)alloc((size_t)NBUK * 128 * 4);
    float* ssA   = (float*)alloc(64 * 4);
    float* ssB   = (float*)alloc(128 * 4);
    unsigned int* gmax = (unsigned int*)alloc(NG * 64 * 4);
    unsigned int* gneg = (unsigned int*)alloc(NG * 64 * 4);

    // bucket partition (also inits gmax/gneg)
    p1count<<<NBLK1, 256, 0, stream>>>(dstp, gmat);
    scanA<<<NBUK, 512, 0, stream>>>(gmat, tot);
    scanB<<<1, 1024, 0, stream>>>(tot, bbase, gmax, gneg);
    p1scatter<<<NBLK1, 256, 0, stream>>>(srcp, dstp, gmat, bbase, sedge);

    // Layer A (edgeA flush writes accA + BN partials)
    uA_kernel<<<(NN + 255) / 256, 256, 0, stream>>>(pos, W1a, b1a, PA, QA);
    edgeA<<<NBUK, 256, 0, stream>>>(PA, QA, sedge, bbase, W2a, b2a, accA, partA);
    bn_final<32><<<1, 1024, 0, stream>>>(partA, NBUK, g1, be1, ssA);

    // Layer B (edgeB flush computes BN partials + graph pool; accB never materialized)
    uB_kernel<<<(NN + 255) / 256, 256, 0, stream>>>(accA, ssA, pos, W1b, b1b, PB, QB);
    edgeB<<<NBUK, 256, 0, stream>>>(PB, QB, sedge, bbase, batch, W2b, b2b, partB, gmax, gneg);
    bn_final<64><<<1, 1024, 0, stream>>>(partB, NBUK, g2, be2, ssB);
    final_gemm<<<1, 128, 0, stream>>>(gmax, gneg, ssB, Wc, bc, (float*)d_out);
}

// Round 17
// 214.287 us; speedup vs baseline: 1.7582x; 1.1728x over previous
//
#include <hip/hip_runtime.h>

#define NN 100000
#define NE 1600000
#define NG 64
#define BSZ 98            // nodes per bucket
#define NBUK 1021         // ceil(NN/BSZ), <= 1024 so scanB fits one block
#define SENTROW 127       // sentinel local row (> BSZ)
#define NBLK1 391         // ceil(NE/4096)
#define EPB 4096          // edges per pass-1 block

typedef __attribute__((ext_vector_type(8))) short bf16x8;
typedef __attribute__((ext_vector_type(4))) float f32x4;

union AFrag { bf16x8 v; uint4 u; };

__device__ __forceinline__ bool finitef(float v) {
    return (__float_as_uint(v) & 0x7F800000u) != 0x7F800000u;
}
__device__ __forceinline__ unsigned short f2bf(float f) {   // RNE, cold paths only
    unsigned int u = __float_as_uint(f);
    u += 0x7fffu + ((u >> 16) & 1u);
    return (unsigned short)(u >> 16);
}
__device__ __forceinline__ unsigned int cvtpk(float lo, float hi) {
    unsigned int r;
    asm("v_cvt_pk_bf16_f32 %0, %1, %2" : "=v"(r) : "v"(lo), "v"(hi));
    return r;
}
__device__ __forceinline__ float bflo(unsigned int q) { return __uint_as_float(q << 16); }
__device__ __forceinline__ float bfhi(unsigned int q) { return __uint_as_float(q & 0xffff0000u); }

// Order-preserving float<->uint bijection: max(float) == atomicMax(uint), identity = 0.
// dec(0) = NaN (no-edge marker), handled downstream by finitef -> 0.
__device__ __forceinline__ unsigned int enc(float f) {
    unsigned int u = __float_as_uint(f);
    return (u & 0x80000000u) ? ~u : (u | 0x80000000u);
}
__device__ __forceinline__ float dec(unsigned int k) {
    unsigned int u = (k & 0x80000000u) ? (k ^ 0x80000000u) : ~k;
    return __uint_as_float(u);
}

// ---------------- bucket partition (atomic-free 2-level) ----------------
__global__ __launch_bounds__(256) void p1count(const int* __restrict__ dst,
                                               int* __restrict__ gmat) {
    __shared__ int h[NBUK];
    int tid = threadIdx.x;
    for (int i = tid; i < NBUK; i += 256) h[i] = 0;
    __syncthreads();
    int e0 = blockIdx.x * EPB;
    #pragma unroll
    for (int i = 0; i < 16; ++i) {
        int e = e0 + tid + i * 256;
        if (e < NE) atomicAdd(&h[dst[e] / BSZ], 1);
    }
    __syncthreads();
    for (int i = tid; i < NBUK; i += 256) gmat[blockIdx.x * NBUK + i] = h[i];
}

__global__ __launch_bounds__(512) void scanA(int* __restrict__ gmat, int* __restrict__ tot) {
    __shared__ int ls[512];
    int b = blockIdx.x, tid = threadIdx.x;
    int v = (tid < NBLK1) ? gmat[tid * NBUK + b] : 0;
    ls[tid] = v;
    __syncthreads();
    for (int o = 1; o < 512; o <<= 1) {
        int t = (tid >= o) ? ls[tid - o] : 0;
        __syncthreads();
        ls[tid] += t;
        __syncthreads();
    }
    if (tid < NBLK1) gmat[tid * NBUK + b] = ls[tid] - v;   // exclusive over blocks
    if (tid == 511) tot[b] = ls[511];
}

__global__ __launch_bounds__(1024) void scanB(const int* __restrict__ tot,
        int* __restrict__ base,
        unsigned int* __restrict__ gmax, unsigned int* __restrict__ gneg) {
    __shared__ int ls[1024];
    int tid = threadIdx.x;
    int v = (tid < NBUK) ? tot[tid] : 0;
    ls[tid] = v;
    __syncthreads();
    for (int o = 1; o < 1024; o <<= 1) {
        int t = (tid >= o) ? ls[tid - o] : 0;
        __syncthreads();
        ls[tid] += t;
        __syncthreads();
    }
    if (tid < NBUK) base[tid] = ls[tid] - v;
    if (tid == 1023) base[NBUK] = ls[1023];
    for (int i = tid; i < NG * 64; i += 1024) { gmax[i] = 0u; gneg[i] = 0u; }
}

__global__ __launch_bounds__(256) void p1scatter(const int* __restrict__ src,
        const int* __restrict__ dst, const int* __restrict__ gmat,
        const int* __restrict__ base, int* __restrict__ sedge) {
    __shared__ int cur[NBUK];
    int tid = threadIdx.x;
    for (int i = tid; i < NBUK; i += 256) cur[i] = base[i] + gmat[blockIdx.x * NBUK + i];
    __syncthreads();
    int e0 = blockIdx.x * EPB;
    #pragma unroll
    for (int i = 0; i < 16; ++i) {
        int e = e0 + tid + i * 256;
        if (e < NE) {
            int d = dst[e];
            int buk = d / BSZ;
            int row = d - buk * BSZ;
            int p = atomicAdd(&cur[buk], 1);
            sedge[p] = src[e] | (row << 20);    // packed: src (20b) | local row (7b)
        }
    }
}

// ---------------- layer A node tables: P = pos@(W1h+W1t)+b1, Q = pos@W1t (bf16) ----------------
__global__ __launch_bounds__(256) void uA_kernel(const float* __restrict__ pos,
        const float* __restrict__ W1, const float* __restrict__ b1,
        unsigned short* __restrict__ PA, unsigned short* __restrict__ QA) {
    __shared__ float sWp[96], sWq[96], sb[32];
    if (threadIdx.x < 96) {
        float wt = W1[96 + threadIdx.x];
        sWq[threadIdx.x] = wt;
        sWp[threadIdx.x] = W1[threadIdx.x] + wt;
    }
    if (threadIdx.x < 32) sb[threadIdx.x] = b1[threadIdx.x];
    __syncthreads();
    int n = blockIdx.x * 256 + threadIdx.x;
    if (n >= NN) return;
    float p0 = pos[n * 3 + 0], p1 = pos[n * 3 + 1], p2 = pos[n * 3 + 2];
    float P[32], Q[32];
    #pragma unroll
    for (int c = 0; c < 32; ++c) {
        P[c] = fmaf(p2, sWp[64 + c], fmaf(p1, sWp[32 + c], fmaf(p0, sWp[c], sb[c])));
        Q[c] = fmaf(p2, sWq[64 + c], fmaf(p1, sWq[32 + c], p0 * sWq[c]));
    }
    uint4* po = (uint4*)(PA + (size_t)n * 32);
    uint4* qo = (uint4*)(QA + (size_t)n * 32);
    #pragma unroll
    for (int q = 0; q < 4; ++q) {
        po[q] = make_uint4(cvtpk(P[8*q],P[8*q+1]), cvtpk(P[8*q+2],P[8*q+3]),
                           cvtpk(P[8*q+4],P[8*q+5]), cvtpk(P[8*q+6],P[8*q+7]));
        qo[q] = make_uint4(cvtpk(Q[8*q],Q[8*q+1]), cvtpk(Q[8*q+2],Q[8*q+3]),
                           cvtpk(Q[8*q+4],Q[8*q+5]), cvtpk(Q[8*q+6],Q[8*q+7]));
    }
}

// ---------------- layer B node tables (BN+ReLU fused in; accA is encoded uints) ----------------
__global__ __launch_bounds__(256) void uB_kernel(const unsigned int* __restrict__ accA,
        const float* __restrict__ ssA, const float* __restrict__ pos,
        const float* __restrict__ W1, const float* __restrict__ b1,
        unsigned short* __restrict__ PB, unsigned short* __restrict__ QB) {
    __shared__ float sW[32 * 64];
    __shared__ float sWt[3 * 64];
    __shared__ float sb[64];
    for (int i = threadIdx.x; i < 32 * 64; i += 256) sW[i] = W1[i];
    if (threadIdx.x < 192) sWt[threadIdx.x] = W1[32 * 64 + threadIdx.x];
    if (threadIdx.x < 64) sb[threadIdx.x] = b1[threadIdx.x];
    __syncthreads();
    int n = blockIdx.x * 256 + threadIdx.x;
    if (n >= NN) return;
    float h[32];
    const uint4* a4 = (const uint4*)(accA + (size_t)n * 32);
    #pragma unroll
    for (int q = 0; q < 8; ++q) {
        uint4 v = a4[q];
        unsigned int vv[4] = {v.x, v.y, v.z, v.w};
        #pragma unroll
        for (int r = 0; r < 4; ++r) {
            int c = 4 * q + r;
            float x = dec(vv[r]);
            x = finitef(x) ? x : 0.f;
            h[c] = fmaxf(fmaf(x, ssA[c], ssA[32 + c]), 0.f);
        }
    }
    float p0 = pos[n * 3 + 0], p1 = pos[n * 3 + 1], p2 = pos[n * 3 + 2];
    float Q[64], P[64];
    #pragma unroll
    for (int c = 0; c < 64; ++c) {
        Q[c] = fmaf(p2, sWt[128 + c], fmaf(p1, sWt[64 + c], p0 * sWt[c]));
        P[c] = Q[c] + sb[c];
    }
    #pragma unroll
    for (int k = 0; k < 32; ++k) {
        float x = h[k];
        #pragma unroll
        for (int c = 0; c < 64; ++c) P[c] = fmaf(x, sW[k * 64 + c], P[c]);
    }
    uint4* po = (uint4*)(PB + (size_t)n * 64);
    uint4* qo = (uint4*)(QB + (size_t)n * 64);
    #pragma unroll
    for (int q = 0; q < 8; ++q) {
        po[q] = make_uint4(cvtpk(P[8*q],P[8*q+1]), cvtpk(P[8*q+2],P[8*q+3]),
                           cvtpk(P[8*q+4],P[8*q+5]), cvtpk(P[8*q+6],P[8*q+7]));
        qo[q] = make_uint4(cvtpk(Q[8*q],Q[8*q+1]), cvtpk(Q[8*q+2],Q[8*q+3]),
                           cvtpk(Q[8*q+4],Q[8*q+5]), cvtpk(Q[8*q+6],Q[8*q+7]));
    }
}

// ---------------- Layer A edges: bucket-exclusive; shfl edge distribution; MFMA bf16;
//                  bank-spread LDS atomics; flush = accA + BN partials ----------------
__global__ __launch_bounds__(256, 4) void edgeA(
        const unsigned short* __restrict__ PA, const unsigned short* __restrict__ QA,
        const int* __restrict__ sedge, const int* __restrict__ bbase,
        const float* __restrict__ W2, const float* __restrict__ b2,
        unsigned int* __restrict__ accA, float* __restrict__ partials) {
    __shared__ __align__(16) short w2f[2 * 64 * 8];
    __shared__ unsigned int nm[32 * 99];      // [ch][row], stride 99 -> bank-spread
    __shared__ float psum[256], psq[256];

    const int tid = threadIdx.x;
    const int b   = blockIdx.x;
    const int nb0 = b * BSZ;
    const int lane = tid & 63, wv = tid >> 6;
    const int kg = lane >> 4;

    #pragma unroll
    for (int ii = 0; ii < 4; ++ii) {
        int i = tid + ii * 256;
        int j = i & 7, ln = (i >> 3) & 63, t = (i >> 9) & 1;
        int k = ((ln >> 4) & 3) * 8 + j, col = (ln & 15) + 16 * t;
        w2f[i] = (short)f2bf(W2[k * 32 + col]);
    }
    for (int i = tid; i < 32 * 99; i += 256) nm[i] = 0;
    __syncthreads();

    float b2v[2];
    #pragma unroll
    for (int t = 0; t < 2; ++t) b2v[t] = b2[(lane & 15) + 16 * t];

    const int bs = bbase[b], be = bbase[b + 1];
    int idx = bs + wv * 64 + lane;
    int myed = (idx < be) ? sedge[idx] : (SENTROW << 20);
    for (int e0 = bs; e0 < be; e0 += 256) {
        int nxt = (idx + 256 < be) ? sedge[idx + 256] : (SENTROW << 20);
        idx += 256;

        int edg[4]; unsigned int rw4[4];
        #pragma unroll
        for (int g = 0; g < 4; ++g) {
            edg[g] = __shfl(myed, g * 16 + (lane & 15), 64);
            unsigned int p = 0;
            #pragma unroll
            for (int r = 0; r < 4; ++r) {
                int e2 = __shfl(myed, g * 16 + kg * 4 + r, 64);
                p |= ((unsigned int)(e2 >> 20) & 0xFFu) << (8 * r);
            }
            rw4[g] = p;
        }

        AFrag af[4];
        #pragma unroll
        for (int g = 0; g < 4; ++g) {
            int s = edg[g] & 0xFFFFF;
            int rq = min(edg[g] >> 20, BSZ - 1);
            uint4 Pq = *(const uint4*)&PA[(size_t)s * 32 + kg * 8];
            uint4 Qq = *(const uint4*)&QA[(size_t)(nb0 + rq) * 32 + kg * 8];
            unsigned int pu[4] = {Pq.x, Pq.y, Pq.z, Pq.w};
            unsigned int qu[4] = {Qq.x, Qq.y, Qq.z, Qq.w};
            unsigned int outw[4];
            #pragma unroll
            for (int p = 0; p < 4; ++p) {
                float vlo = fmaxf(bflo(pu[p]) - bflo(qu[p]), 0.f);
                float vhi = fmaxf(bfhi(pu[p]) - bfhi(qu[p]), 0.f);
                outw[p] = cvtpk(vlo, vhi);
            }
            af[g].u = make_uint4(outw[0], outw[1], outw[2], outw[3]);
        }

        #pragma unroll
        for (int t = 0; t < 2; ++t) {
            bf16x8 bfr = *(const bf16x8*)&w2f[(t * 64 + lane) * 8];
            int ch = t * 16 + (lane & 15);
            #pragma unroll
            for (int g = 0; g < 4; ++g) {
                f32x4 c = {b2v[t], b2v[t], b2v[t], b2v[t]};
                f32x4 acc = __builtin_amdgcn_mfma_f32_16x16x32_bf16(af[g].v, bfr, c, 0, 0, 0);
                #pragma unroll
                for (int r = 0; r < 4; ++r) {
                    int rr = (rw4[g] >> (8 * r)) & 0xFF;
                    if (rr < BSZ) atomicMax(&nm[ch * 99 + rr], enc(acc[r]));
                }
            }
        }
        myed = nxt;
    }

    __syncthreads();
    // flush: write accA (exclusive owner) + BN partial sums over this bucket's nodes
    {
        int c = tid & 31, sub = tid >> 5;            // 8 row-groups
        float s = 0.f, q = 0.f;
        for (int nl = sub; nl < BSZ; nl += 8) {
            int n = nb0 + nl;
            if (n >= NN) break;
            unsigned int k = nm[c * 99 + nl];
            accA[(size_t)n * 32 + c] = k;
            float v = dec(k);
            v = finitef(v) ? v : 0.f;
            s += v; q = fmaf(v, v, q);
        }
        psum[tid] = s; psq[tid] = q;
    }
    __syncthreads();
    if (tid < 128) { psum[tid] += psum[tid + 128]; psq[tid] += psq[tid + 128]; }
    __syncthreads();
    if (tid < 64)  { psum[tid] += psum[tid + 64];  psq[tid] += psq[tid + 64]; }
    __syncthreads();
    if (tid < 32) {
        partials[b * 64 + tid]      = psum[tid] + psum[tid + 32];
        partials[b * 64 + 32 + tid] = psq[tid]  + psq[tid + 32];
    }
}

// ---------------- Layer B edges: 64 channels, K=64; flush = BN partials + graph pool ----------------
__global__ __launch_bounds__(256, 4) void edgeB(
        const unsigned short* __restrict__ PB, const unsigned short* __restrict__ QB,
        const int* __restrict__ sedge, const int* __restrict__ bbase,
        const int* __restrict__ batch,
        const float* __restrict__ W2, const float* __restrict__ b2,
        float* __restrict__ partials,
        unsigned int* __restrict__ gmax, unsigned int* __restrict__ gneg) {
    __shared__ __align__(16) short w2f[2 * 4 * 64 * 8];
    __shared__ unsigned int nm[64 * 99];      // [ch][row], stride 99
    __shared__ float psum[256], psq[256];

    const int tid = threadIdx.x;
    const int b   = blockIdx.x;
    const int nb0 = b * BSZ;
    const int lane = tid & 63, wv = tid >> 6;
    const int kg = lane >> 4;

    #pragma unroll
    for (int ii = 0; ii < 16; ++ii) {
        int i = tid + ii * 256;
        int j = i & 7, ln = (i >> 3) & 63, t = (i >> 9) & 3, ks = (i >> 11) & 1;
        int k = ks * 32 + ((ln >> 4) & 3) * 8 + j, col = (ln & 15) + 16 * t;
        w2f[i] = (short)f2bf(W2[k * 64 + col]);
    }
    for (int i = tid; i < 64 * 99; i += 256) nm[i] = 0;
    __syncthreads();

    float b2v[4];
    #pragma unroll
    for (int t = 0; t < 4; ++t) b2v[t] = b2[(lane & 15) + 16 * t];

    const int bs = bbase[b], be = bbase[b + 1];
    int idx = bs + wv * 64 + lane;
    int myed = (idx < be) ? sedge[idx] : (SENTROW << 20);
    for (int e0 = bs; e0 < be; e0 += 256) {
        int nxt = (idx + 256 < be) ? sedge[idx + 256] : (SENTROW << 20);
        idx += 256;

        int edg[4]; unsigned int rw4[4];
        #pragma unroll
        for (int g = 0; g < 4; ++g) {
            edg[g] = __shfl(myed, g * 16 + (lane & 15), 64);
            unsigned int p = 0;
            #pragma unroll
            for (int r = 0; r < 4; ++r) {
                int e2 = __shfl(myed, g * 16 + kg * 4 + r, 64);
                p |= ((unsigned int)(e2 >> 20) & 0xFFu) << (8 * r);
            }
            rw4[g] = p;
        }

        AFrag af[4][2];
        #pragma unroll
        for (int g = 0; g < 4; ++g) {
            int s = edg[g] & 0xFFFFF;
            int rq = min(edg[g] >> 20, BSZ - 1);
            #pragma unroll
            for (int ks = 0; ks < 2; ++ks) {
                uint4 Pq = *(const uint4*)&PB[(size_t)s * 64 + ks * 32 + kg * 8];
                uint4 Qq = *(const uint4*)&QB[(size_t)(nb0 + rq) * 64 + ks * 32 + kg * 8];
                unsigned int pu[4] = {Pq.x, Pq.y, Pq.z, Pq.w};
                unsigned int qu[4] = {Qq.x, Qq.y, Qq.z, Qq.w};
                unsigned int outw[4];
                #pragma unroll
                for (int p = 0; p < 4; ++p) {
                    float vlo = fmaxf(bflo(pu[p]) - bflo(qu[p]), 0.f);
                    float vhi = fmaxf(bfhi(pu[p]) - bfhi(qu[p]), 0.f);
                    outw[p] = cvtpk(vlo, vhi);
                }
                af[g][ks].u = make_uint4(outw[0], outw[1], outw[2], outw[3]);
            }
        }

        #pragma unroll
        for (int t = 0; t < 4; ++t) {
            bf16x8 bf0 = *(const bf16x8*)&w2f[((0 * 4 + t) * 64 + lane) * 8];
            bf16x8 bf1 = *(const bf16x8*)&w2f[((1 * 4 + t) * 64 + lane) * 8];
            int ch = t * 16 + (lane & 15);
            #pragma unroll
            for (int g = 0; g < 4; ++g) {
                f32x4 c = {b2v[t], b2v[t], b2v[t], b2v[t]};
                c = __builtin_amdgcn_mfma_f32_16x16x32_bf16(af[g][0].v, bf0, c, 0, 0, 0);
                f32x4 acc = __builtin_amdgcn_mfma_f32_16x16x32_bf16(af[g][1].v, bf1, c, 0, 0, 0);
                #pragma unroll
                for (int r = 0; r < 4; ++r) {
                    int rr = (rw4[g] >> (8 * r)) & 0xFF;
                    if (rr < BSZ) atomicMax(&nm[ch * 99 + rr], enc(acc[r]));
                }
            }
        }
        myed = nxt;
    }

    __syncthreads();
    // flush: BN partial sums + graph raw max/-min pool (batch sorted -> run-max)
    {
        int c = tid & 63, sub = tid >> 6;            // 4 row-groups
        float s = 0.f, q = 0.f;
        float rmax = 0.f, rneg = 0.f; int curg = -1;
        for (int nl = sub; nl < BSZ; nl += 4) {
            int n = nb0 + nl;
            if (n >= NN) break;
            float v = dec(nm[c * 99 + nl]);
            v = finitef(v) ? v : 0.f;
            s += v; q = fmaf(v, v, q);
            int g = batch[n];
            if (g != curg) {
                if (curg >= 0) {
                    atomicMax(&gmax[curg * 64 + c], enc(rmax));
                    atomicMax(&gneg[curg * 64 + c], enc(rneg));
                }
                curg = g; rmax = v; rneg = -v;
            } else {
                rmax = fmaxf(rmax, v); rneg = fmaxf(rneg, -v);
            }
        }
        if (curg >= 0) {
            atomicMax(&gmax[curg * 64 + c], enc(rmax));
            atomicMax(&gneg[curg * 64 + c], enc(rneg));
        }
        psum[tid] = s; psq[tid] = q;
    }
    __syncthreads();
    if (tid < 128) { psum[tid] += psum[tid + 128]; psq[tid] += psq[tid + 128]; }
    __syncthreads();
    if (tid < 64) {
        partials[b * 128 + tid]      = psum[tid] + psum[tid + 64];
        partials[b * 128 + 64 + tid] = psq[tid]  + psq[tid + 64];
    }
}

// ---------------- parallel final BN reduction: 1024 threads, chunked + tree ----------------
template <int C>
__global__ __launch_bounds__(1024) void bn_final(const float* __restrict__ partials, int nblocks,
                         const float* __restrict__ gamma, const float* __restrict__ beta,
                         float* __restrict__ ss) {
    __shared__ float lsum[1024], lsq[1024];
    const int NCH = 1024 / C;
    int tid = threadIdx.x;
    int c = tid & (C - 1);
    int chunk = tid / C;
    float s = 0.f, q = 0.f;
    for (int b = chunk; b < nblocks; b += NCH) {
        s += partials[b * 2 * C + c];
        q += partials[b * 2 * C + C + c];
    }
    lsum[chunk * C + c] = s; lsq[chunk * C + c] = q;
    __syncthreads();
    #pragma unroll
    for (int o = 512; o >= C; o >>= 1) {
        if (tid < o && o >= C) {
            lsum[tid] += lsum[tid + o];
            lsq[tid]  += lsq[tid + o];
        }
        __syncthreads();
    }
    if (tid < C) {
        float mu  = lsum[tid] / (float)NN;
        float var = fmaxf(lsq[tid] / (float)NN - mu * mu, 0.f);
        float inv = rsqrtf(var + 1e-5f);
        float sc  = gamma[tid] * inv;
        ss[tid]     = sc;
        ss[C + tid] = fmaf(-mu, sc, beta[tid]);
    }
}

// ---------------- final: BN affine+relu on pooled extrema, then 64x64x2 GEMM ----------------
__global__ void final_gemm(const unsigned int* __restrict__ gmax,
                           const unsigned int* __restrict__ gneg,
                           const float* __restrict__ ss, const float* __restrict__ Wc,
                           const float* __restrict__ bc, float* __restrict__ out) {
    int t = threadIdx.x;
    if (t >= NG * 2) return;
    int g = t >> 1, o = t & 1;
    float s = bc[o];
    for (int k = 0; k < 64; ++k) {
        float sc = ss[k], sh = ss[64 + k];
        float xm = dec(gmax[g * 64 + k]), xn = dec(gneg[g * 64 + k]);
        float x = (sc >= 0.f) ? xm : -xn;
        float v = finitef(x) ? fmaxf(fmaf(sc, x, sh), 0.f) : 0.f;   // empty graph -> 0
        s = fmaf(v, Wc[k * 2 + o], s);
    }
    out[t] = s;
}

extern "C" void kernel_launch(void* const* d_in, const int* in_sizes, int n_in,
                              void* d_out, int out_size, void* d_ws, size_t ws_size,
                              hipStream_t stream) {
    const float* pos   = (const float*)d_in[0];
    const int*   ei    = (const int*)d_in[1];
    const int*   batch = (const int*)d_in[2];
    const float* W1a = (const float*)d_in[3];
    const float* b1a = (const float*)d_in[4];
    const float* W2a = (const float*)d_in[5];
    const float* b2a = (const float*)d_in[6];
    const float* g1  = (const float*)d_in[7];
    const float* be1 = (const float*)d_in[8];
    const float* W1b = (const float*)d_in[9];
    const float* b1b = (const float*)d_in[10];
    const float* W2b = (const float*)d_in[11];
    const float* b2b = (const float*)d_in[12];
    const float* g2  = (const float*)d_in[13];
    const float* be2 = (const float*)d_in[14];
    const float* Wc  = (const float*)d_in[15];
    const float* bc  = (const float*)d_in[16];
    const int* srcp = ei;
    const int* dstp = ei + NE;

    char* base_p = (char*)d_ws;
    size_t ofs = 0;
    auto alloc = [&](size_t bytes) { char* p = base_p + ofs; ofs = (ofs + bytes + 255) & ~(size_t)255; return p; };
    int*   gmat  = (int*)alloc((size_t)NBLK1 * NBUK * 4);
    int*   tot   = (int*)alloc(NBUK * 4);
    int*   bbase = (int*)alloc((NBUK + 1) * 4);
    int*   sedge = (int*)alloc((size_t)NE * 4);                       // packed src|row, 6.4 MB
    unsigned short* PA = (unsigned short*)alloc((size_t)NN * 32 * 2);
    unsigned short* QA = (unsigned short*)alloc((size_t)NN * 32 * 2);
    unsigned short* PB = PA;                                           // spans PA+QA (12.8 MB)
    unsigned short* QB = (unsigned short*)alloc((size_t)NN * 64 * 2);
    unsigned int* accA = (unsigned int*)alloc((size_t)NN * 32 * 4);   // written fully by edgeA flush
    float* partA = (float*)alloc((size_t)NBUK * 64 * 4);
    float* partB = (float*)alloc((size_t)NBUK * 128 * 4);
    float* ssA   = (float*)alloc(64 * 4);
    float* ssB   = (float*)alloc(128 * 4);
    unsigned int* gmax = (unsigned int*)alloc(NG * 64 * 4);
    unsigned int* gneg = (unsigned int*)alloc(NG * 64 * 4);

    // bucket partition (also inits gmax/gneg)
    p1count<<<NBLK1, 256, 0, stream>>>(dstp, gmat);
    scanA<<<NBUK, 512, 0, stream>>>(gmat, tot);
    scanB<<<1, 1024, 0, stream>>>(tot, bbase, gmax, gneg);
    p1scatter<<<NBLK1, 256, 0, stream>>>(srcp, dstp, gmat, bbase, sedge);

    // Layer A (edgeA flush writes accA + BN partials)
    uA_kernel<<<(NN + 255) / 256, 256, 0, stream>>>(pos, W1a, b1a, PA, QA);
    edgeA<<<NBUK, 256, 0, stream>>>(PA, QA, sedge, bbase, W2a, b2a, accA, partA);
    bn_final<32><<<1, 1024, 0, stream>>>(partA, NBUK, g1, be1, ssA);

    // Layer B (edgeB flush computes BN partials + graph pool; accB never materialized)
    uB_kernel<<<(NN + 255) / 256, 256, 0, stream>>>(accA, ssA, pos, W1b, b1b, PB, QB);
    edgeB<<<NBUK, 256, 0, stream>>>(PB, QB, sedge, bbase, batch, W2b, b2b, partB, gmax, gneg);
    bn_final<64><<<1, 1024, 0, stream>>>(partB, NBUK, g2, be2, ssB);
    final_gemm<<<1, 128, 0, stream>>>(gmax, gneg, ssB, Wc, bc, (float*)d_out);
}